// Round 1
// baseline (412.907 us; speedup 1.0000x reference)
//
#include <hip/hip_runtime.h>

#define NTOK (8 * 16 * 32 * 32)  // 131072 tokens
#define NE 1024
#define ED 64

__global__ __launch_bounds__(256) void vq_kernel(
    const float* __restrict__ z,
    const float* __restrict__ emb,
    float* __restrict__ zq_out,
    float* __restrict__ idx_out)
{
    // ---- per-block: ||e||^2 for all 1024 embeddings into LDS ----
    __shared__ float s2[NE];
    for (int e = threadIdx.x; e < NE; e += 256) {
        const float* ep = emb + e * ED;
        // numpy-style 8-way unrolled pairwise sum of squares
        float r0 = 0.f, r1 = 0.f, r2 = 0.f, r3 = 0.f;
        float r4 = 0.f, r5 = 0.f, r6 = 0.f, r7 = 0.f;
#pragma unroll
        for (int d = 0; d < ED; d += 8) {
            float v0 = ep[d + 0], v1 = ep[d + 1], v2 = ep[d + 2], v3 = ep[d + 3];
            float v4 = ep[d + 4], v5 = ep[d + 5], v6 = ep[d + 6], v7 = ep[d + 7];
            r0 += v0 * v0; r1 += v1 * v1; r2 += v2 * v2; r3 += v3 * v3;
            r4 += v4 * v4; r5 += v5 * v5; r6 += v6 * v6; r7 += v7 * v7;
        }
        s2[e] = ((r0 + r1) + (r2 + r3)) + ((r4 + r5) + (r6 + r7));
    }
    __syncthreads();

    const int t = blockIdx.x * 256 + threadIdx.x;

    // ---- load this token's z vector into registers (16 x float4) ----
    float zr[ED];
    const float4* zp = (const float4*)(z + (size_t)t * ED);
#pragma unroll
    for (int i = 0; i < ED / 4; ++i) {
        float4 v = zp[i];
        zr[4 * i + 0] = v.x;
        zr[4 * i + 1] = v.y;
        zr[4 * i + 2] = v.z;
        zr[4 * i + 3] = v.w;
    }

    // ---- S1 = ||z||^2, numpy-style 8-way pairwise ----
    float r0 = 0.f, r1 = 0.f, r2 = 0.f, r3 = 0.f;
    float r4 = 0.f, r5 = 0.f, r6 = 0.f, r7 = 0.f;
#pragma unroll
    for (int d = 0; d < ED; d += 8) {
        r0 += zr[d + 0] * zr[d + 0];
        r1 += zr[d + 1] * zr[d + 1];
        r2 += zr[d + 2] * zr[d + 2];
        r3 += zr[d + 3] * zr[d + 3];
        r4 += zr[d + 4] * zr[d + 4];
        r5 += zr[d + 5] * zr[d + 5];
        r6 += zr[d + 6] * zr[d + 6];
        r7 += zr[d + 7] * zr[d + 7];
    }
    const float s1 = ((r0 + r1) + (r2 + r3)) + ((r4 + r5) + (r6 + r7));

    // ---- scan all embeddings; strict < keeps first (numpy argmin tie-break) ----
    float best = 3.4e38f;
    int bi = 0;
    for (int e = 0; e < NE; ++e) {
        const float* ep = emb + e * ED;  // wave-uniform address -> s_load path
        float a0 = 0.f, a1 = 0.f, a2 = 0.f, a3 = 0.f;
#pragma unroll
        for (int d = 0; d < ED; d += 4) {
            a0 = fmaf(zr[d + 0], ep[d + 0], a0);
            a1 = fmaf(zr[d + 1], ep[d + 1], a1);
            a2 = fmaf(zr[d + 2], ep[d + 2], a2);
            a3 = fmaf(zr[d + 3], ep[d + 3], a3);
        }
        const float g = (a0 + a1) + (a2 + a3);
        const float dist = (s1 + s2[e]) - 2.0f * g;
        if (dist < best) { best = dist; bi = e; }
    }

    // ---- write z_q = emb[bi] and idx (as float) ----
    const float4* eb = (const float4*)(emb + (size_t)bi * ED);
    float4* oq = (float4*)(zq_out + (size_t)t * ED);
#pragma unroll
    for (int i = 0; i < ED / 4; ++i) oq[i] = eb[i];
    idx_out[t] = (float)bi;
}

extern "C" void kernel_launch(void* const* d_in, const int* in_sizes, int n_in,
                              void* d_out, int out_size, void* d_ws, size_t ws_size,
                              hipStream_t stream) {
    const float* z = (const float*)d_in[0];
    const float* emb = (const float*)d_in[1];
    float* out = (float*)d_out;
    float* zq = out;                              // 131072*64 floats
    float* idx = out + (size_t)NTOK * ED;         // 131072 floats (index values)

    vq_kernel<<<NTOK / 256, 256, 0, stream>>>(z, emb, zq, idx);
}

// Round 2
// 314.847 us; speedup vs baseline: 1.3115x; 1.3115x over previous
//
#include <hip/hip_runtime.h>

#define NTOK (8 * 16 * 32 * 32)  // 131072 tokens
#define NE 1024
#define ED 64
#define TPB 256                  // 4 waves per block
#define TOK_PER_BLK 64           // one token per lane
#define NCHUNK 4
#define CHUNK (NE / NCHUNK)      // 256 embeddings per wave

__global__ __launch_bounds__(TPB, 4) void vq_kernel(
    const float* __restrict__ z,
    const float* __restrict__ emb,
    float* __restrict__ zq_out,
    float* __restrict__ idx_out)
{
    __shared__ float s2[NE];
    __shared__ float red_d[NCHUNK][TOK_PER_BLK];
    __shared__ int   red_i[NCHUNK][TOK_PER_BLK];

    // ---- ||e||^2 for all 1024 embeddings (numpy-style 8-way pairwise) ----
    for (int e = threadIdx.x; e < NE; e += TPB) {
        const float* ep = emb + e * ED;
        float r0 = 0.f, r1 = 0.f, r2 = 0.f, r3 = 0.f;
        float r4 = 0.f, r5 = 0.f, r6 = 0.f, r7 = 0.f;
#pragma unroll
        for (int d = 0; d < ED; d += 8) {
            float v0 = ep[d + 0], v1 = ep[d + 1], v2 = ep[d + 2], v3 = ep[d + 3];
            float v4 = ep[d + 4], v5 = ep[d + 5], v6 = ep[d + 6], v7 = ep[d + 7];
            r0 += v0 * v0; r1 += v1 * v1; r2 += v2 * v2; r3 += v3 * v3;
            r4 += v4 * v4; r5 += v5 * v5; r6 += v6 * v6; r7 += v7 * v7;
        }
        s2[e] = ((r0 + r1) + (r2 + r3)) + ((r4 + r5) + (r6 + r7));
    }

    const int lane = threadIdx.x & 63;
    const int wave = __builtin_amdgcn_readfirstlane(threadIdx.x >> 6);
    const int t = blockIdx.x * TOK_PER_BLK + lane;

    // ---- token's z vector -> registers (kept resident: 128-VGPR budget) ----
    float zr[ED];
    const float4* zp = (const float4*)(z + (size_t)t * ED);
#pragma unroll
    for (int i = 0; i < ED / 4; ++i) {
        float4 v = zp[i];
        zr[4 * i + 0] = v.x;
        zr[4 * i + 1] = v.y;
        zr[4 * i + 2] = v.z;
        zr[4 * i + 3] = v.w;
    }

    // ---- S1 = ||z||^2 (numpy-style 8-way pairwise) ----
    float r0 = 0.f, r1 = 0.f, r2 = 0.f, r3 = 0.f;
    float r4 = 0.f, r5 = 0.f, r6 = 0.f, r7 = 0.f;
#pragma unroll
    for (int d = 0; d < ED; d += 8) {
        r0 += zr[d + 0] * zr[d + 0];
        r1 += zr[d + 1] * zr[d + 1];
        r2 += zr[d + 2] * zr[d + 2];
        r3 += zr[d + 3] * zr[d + 3];
        r4 += zr[d + 4] * zr[d + 4];
        r5 += zr[d + 5] * zr[d + 5];
        r6 += zr[d + 6] * zr[d + 6];
        r7 += zr[d + 7] * zr[d + 7];
    }
    const float s1 = ((r0 + r1) + (r2 + r3)) + ((r4 + r5) + (r6 + r7));

    __syncthreads();  // s2 ready

    // ---- each wave scans its 256-embedding chunk (scalar emb loads) ----
    float best = 3.4e38f;
    int bi = 0;
    const int e0 = wave * CHUNK;
    for (int e = e0; e < e0 + CHUNK; ++e) {
        const float* ep = emb + e * ED;  // wave-uniform -> s_load
        float a0 = 0.f, a1 = 0.f, a2 = 0.f, a3 = 0.f;
#pragma unroll
        for (int d = 0; d < ED; d += 4) {
            a0 = fmaf(zr[d + 0], ep[d + 0], a0);
            a1 = fmaf(zr[d + 1], ep[d + 1], a1);
            a2 = fmaf(zr[d + 2], ep[d + 2], a2);
            a3 = fmaf(zr[d + 3], ep[d + 3], a3);
        }
        const float g = (a0 + a1) + (a2 + a3);
        const float dist = (s1 + s2[e]) - 2.0f * g;
        if (dist < best) { best = dist; bi = e; }  // strict < : first index wins
    }

    red_d[wave][lane] = best;
    red_i[wave][lane] = bi;
    __syncthreads();

    // ---- cross-chunk argmin (chunks in index order; strict < keeps lowest e) ----
    float wd = red_d[0][lane];
    int wi = red_i[0][lane];
#pragma unroll
    for (int c = 1; c < NCHUNK; ++c) {
        float d2 = red_d[c][lane];
        int i2 = red_i[c][lane];
        if (d2 < wd) { wd = d2; wi = i2; }
    }

    // ---- outputs: all 4 waves cooperate on z_q row copy ----
    const float4* eb = (const float4*)(emb + (size_t)wi * ED);
    float4* oq = (float4*)(zq_out + (size_t)t * ED);
#pragma unroll
    for (int i = 0; i < 4; ++i) oq[wave * 4 + i] = eb[wave * 4 + i];
    if (wave == 0) idx_out[t] = (float)wi;
}

extern "C" void kernel_launch(void* const* d_in, const int* in_sizes, int n_in,
                              void* d_out, int out_size, void* d_ws, size_t ws_size,
                              hipStream_t stream) {
    const float* z = (const float*)d_in[0];
    const float* emb = (const float*)d_in[1];
    float* out = (float*)d_out;
    float* zq = out;                       // 131072*64 floats
    float* idx = out + (size_t)NTOK * ED;  // 131072 floats

    vq_kernel<<<NTOK / TOK_PER_BLK, TPB, 0, stream>>>(z, emb, zq, idx);
}